// Round 9
// baseline (445.034 us; speedup 1.0000x reference)
//
#include <hip/hip_runtime.h>

#define NN 50000
#define EE 600000
#define DD 128
#define GG 256
#define LL 5
#define OO 10
#define BN_EPS 1e-5f
#define CPAD 513      // 512 combos + 1 sentinel (-1e30) row per layer
#define ESTRIDE 48    // fixed CSR slots per node, pad-to-16 (P(deg>48)~0 at lambda=12)
#define SENT (512u << 16)

// prep kernel block-range sizes
#define B_CVT   3125                       // NN*DD/8 / 256
#define B_COMBO 1283                       // ceil(LL*CPAD*DD / 256)
#define B_WT    160                        // 10 mats x 16 (32x32) tiles
#define B_EFILL 2344                       // ceil(NN*ESTRIDE/4 / 256)
#define B_INV   1
#define B_POOL0 391                        // ceil(NN/128)
#define B_PREP  (B_CVT + B_COMBO + B_WT + B_EFILL + B_INV + B_POOL0)

typedef __attribute__((ext_vector_type(8))) short short8;
typedef __attribute__((ext_vector_type(16))) float float16;

__device__ __forceinline__ unsigned short f2b(float f) {   // fp32 -> bf16 RNE
    unsigned u = __float_as_uint(f);
    unsigned r = u + 0x7FFFu + ((u >> 16) & 1u);
    return (unsigned short)(r >> 16);
}
__device__ __forceinline__ unsigned pk2(float lo, float hi) {
    return (unsigned)f2b(lo) | ((unsigned)f2b(hi) << 16);
}
__device__ __forceinline__ float blo(unsigned u) { return __uint_as_float(u << 16); }
__device__ __forceinline__ float bhi(unsigned u) { return __uint_as_float(u & 0xFFFF0000u); }

// ====== mega prep: cvt_x | combo | Wt-transpose | e_info sentinel fill | inv | pool0 ======
__launch_bounds__(256)
__global__ void prep(const float* __restrict__ x, const int* __restrict__ batch,
                     const float* __restrict__ bond,
                     const float* __restrict__ w1, const float* __restrict__ w2,
                     unsigned* __restrict__ xb4, unsigned short* __restrict__ combo,
                     short* __restrict__ wt, unsigned* __restrict__ e_info,
                     float* __restrict__ inv, float* __restrict__ pooled0) {
    const int bid = blockIdx.x, t = threadIdx.x;
    if (bid < B_CVT) {
        // x (fp32) -> xb (bf16), 8 elems/thread
        int gid = bid * 256 + t;
        const float4* xp = (const float4*)(x + (size_t)gid * 8);
        float4 a = xp[0], b = xp[1];
        uint4 o;
        o.x = pk2(a.x, a.y); o.y = pk2(a.z, a.w);
        o.z = pk2(b.x, b.y); o.w = pk2(b.z, b.w);
        ((uint4*)xb4)[gid] = o;
    } else if (bid < B_CVT + B_COMBO) {
        int e = (bid - B_CVT) * 256 + t;
        if (e < LL * CPAD * DD) {
            int l = e / (CPAD * DD), rem = e - l * (CPAD * DD);
            int c = rem / DD, d = rem - c * DD;
            float s;
            if (c == 512) s = -1e30f;                     // sentinel: relu(x+s)==0
            else {
                const float* b_ = bond + (size_t)l * 3 * 8 * DD;
                s = b_[(c & 7) * DD + d] + b_[(8 + ((c >> 3) & 7)) * DD + d]
                  + b_[(16 + (c >> 6)) * DD + d];
            }
            combo[e] = f2b(s);
        }
    } else if (bid < B_CVT + B_COMBO + B_WT) {
        // coalesced transpose: wt[mat][c][k] = bf16(W[mat][k][c]), 32x32 LDS tiles
        __shared__ float tile[32][33];
        int b = bid - B_CVT - B_COMBO;
        int mat = b >> 4, tl = b & 15;
        int k0 = (tl >> 2) * 32, c0 = (tl & 3) * 32;
        const float* W = (mat < 5) ? (w1 + (size_t)mat * DD * DD)
                                   : (w2 + (size_t)(mat - 5) * DD * DD);
        int j = t & 31, q = t >> 5;
#pragma unroll
        for (int rr = 0; rr < 4; ++rr) {
            int row = q + rr * 8;
            tile[row][j] = W[(size_t)(k0 + row) * DD + c0 + j];
        }
        __syncthreads();
#pragma unroll
        for (int rr = 0; rr < 4; ++rr) {
            int cr = q + rr * 8;
            wt[(size_t)mat * DD * DD + (size_t)(c0 + cr) * DD + k0 + j] = (short)f2b(tile[j][cr]);
        }
    } else if (bid < B_CVT + B_COMBO + B_WT + B_EFILL) {
        // sentinel-fill e_info (uint4 per thread)
        int gid = (bid - B_CVT - B_COMBO - B_WT) * 256 + t;
        if (gid < NN * ESTRIDE / 4)
            ((uint4*)e_info)[gid] = make_uint4(SENT, SENT, SENT, SENT);
    } else if (bid < B_CVT + B_COMBO + B_WT + B_EFILL + B_INV) {
        // inv[g] via binary search on sorted batch
        __shared__ int sg[GG + 1];
        int g = t, lo = 0, hi = NN;
        while (lo < hi) { int m = (lo + hi) >> 1; if (batch[m] < g) lo = m + 1; else hi = m; }
        sg[g] = lo;
        if (g == 0) sg[GG] = NN;
        __syncthreads();
        inv[g] = 1.0f / fmaxf((float)(sg[g + 1] - sg[g]), 1.0f);
    } else {
        // layer-0 pooling of raw fp32 x: 128 nodes/block, per-graph partials
        int b = bid - (B_CVT + B_COMBO + B_WT + B_EFILL + B_INV);
        int n0 = b * 128;
        __shared__ int sb[128];
        __shared__ float part[4][DD];
        if (t < 128) { int row = n0 + t; sb[t] = (row < NN) ? batch[row] : -1; }
        ((float*)part)[t] = 0.f;
        ((float*)part)[t + 256] = 0.f;
        __syncthreads();
        int gmin = sb[0];
        int col = t & 127, rh = t >> 7;
        float pg[4] = {0.f, 0.f, 0.f, 0.f};
        for (int r = rh; r < 128; r += 2) {
            int s = sb[r];
            float v = (s >= 0) ? x[(size_t)(n0 + r) * DD + col] : 0.f;
            int dg = s - gmin;
#pragma unroll
            for (int jj = 0; jj < 4; ++jj) pg[jj] += (dg == jj) ? v : 0.f;
        }
#pragma unroll
        for (int jj = 0; jj < 4; ++jj)
            if (pg[jj] != 0.f) atomicAdd(&part[jj][col], pg[jj]);
        __syncthreads();
        for (int q2 = t; q2 < 4 * DD; q2 += 256) {
            int jj = q2 >> 7, c2 = q2 & 127;
            float v = part[jj][c2];
            if (v != 0.f && gmin + jj < GG) atomicAdd(&pooled0[(gmin + jj) * DD + c2], v);
        }
    }
}

// payload: src (16b) | combo index (10b) << 16.  epos[n] = running count (pre-zeroed).
__launch_bounds__(256)
__global__ void scatter_edges(const int* __restrict__ ei, const int* __restrict__ eattr,
                              int* __restrict__ epos, unsigned* __restrict__ e_info) {
    int e = blockIdx.x * 256 + threadIdx.x;
    if (e >= EE) return;
    int dst = ei[EE + e];
    int pos = dst * ESTRIDE + atomicAdd(&epos[dst], 1);
    unsigned cidx = (unsigned)eattr[e * 3 + 0] | ((unsigned)eattr[e * 3 + 1] << 3)
                  | ((unsigned)eattr[e * 3 + 2] << 6);
    e_info[pos] = (unsigned)ei[e] | (cidx << 16);
}

// ====== CSR aggregation + residual: 16 lanes x 8 feats per edge, 16 edges per iter ======
// hin = x + sum relu(x_src + combo); bf16 in/out, fp32 accumulate. Lists sentinel-padded.
__launch_bounds__(256)
__global__ void aggr_csr(const unsigned short* __restrict__ xin,
                         const int* __restrict__ epos,
                         const unsigned* __restrict__ e_info,
                         const unsigned short* __restrict__ combo,
                         unsigned short* __restrict__ hin) {
    int node = blockIdx.x * 4 + (threadIdx.x >> 6);
    int lane = threadIdx.x & 63;
    if (node >= NN) return;
    const int base = node * ESTRIDE;
    const int deg  = epos[node];
    const int pe   = base + ((deg + 15) & ~15);
    const int eg   = lane >> 4;          // edge sub-group 0..3
    const int f    = (lane & 15) * 8;    // feature offset
    float acc[8];
#pragma unroll
    for (int i = 0; i < 8; ++i) acc[i] = 0.f;

    for (int p = base; p < pe; p += 16) {
        unsigned i0 = e_info[p + eg];
        unsigned i1 = e_info[p + 4 + eg];
        unsigned i2 = e_info[p + 8 + eg];
        unsigned i3 = e_info[p + 12 + eg];
        uint4 xv0 = *(const uint4*)&xin[(size_t)(i0 & 0xFFFFu) * DD + f];
        uint4 cv0 = *(const uint4*)&combo[(size_t)(i0 >> 16) * DD + f];
        uint4 xv1 = *(const uint4*)&xin[(size_t)(i1 & 0xFFFFu) * DD + f];
        uint4 cv1 = *(const uint4*)&combo[(size_t)(i1 >> 16) * DD + f];
        uint4 xv2 = *(const uint4*)&xin[(size_t)(i2 & 0xFFFFu) * DD + f];
        uint4 cv2 = *(const uint4*)&combo[(size_t)(i2 >> 16) * DD + f];
        uint4 xv3 = *(const uint4*)&xin[(size_t)(i3 & 0xFFFFu) * DD + f];
        uint4 cv3 = *(const uint4*)&combo[(size_t)(i3 >> 16) * DD + f];
        acc[0] += fmaxf(blo(xv0.x) + blo(cv0.x), 0.f) + fmaxf(blo(xv1.x) + blo(cv1.x), 0.f)
                + fmaxf(blo(xv2.x) + blo(cv2.x), 0.f) + fmaxf(blo(xv3.x) + blo(cv3.x), 0.f);
        acc[1] += fmaxf(bhi(xv0.x) + bhi(cv0.x), 0.f) + fmaxf(bhi(xv1.x) + bhi(cv1.x), 0.f)
                + fmaxf(bhi(xv2.x) + bhi(cv2.x), 0.f) + fmaxf(bhi(xv3.x) + bhi(cv3.x), 0.f);
        acc[2] += fmaxf(blo(xv0.y) + blo(cv0.y), 0.f) + fmaxf(blo(xv1.y) + blo(cv1.y), 0.f)
                + fmaxf(blo(xv2.y) + blo(cv2.y), 0.f) + fmaxf(blo(xv3.y) + blo(cv3.y), 0.f);
        acc[3] += fmaxf(bhi(xv0.y) + bhi(cv0.y), 0.f) + fmaxf(bhi(xv1.y) + bhi(cv1.y), 0.f)
                + fmaxf(bhi(xv2.y) + bhi(cv2.y), 0.f) + fmaxf(bhi(xv3.y) + bhi(cv3.y), 0.f);
        acc[4] += fmaxf(blo(xv0.z) + blo(cv0.z), 0.f) + fmaxf(blo(xv1.z) + blo(cv1.z), 0.f)
                + fmaxf(blo(xv2.z) + blo(cv2.z), 0.f) + fmaxf(blo(xv3.z) + blo(cv3.z), 0.f);
        acc[5] += fmaxf(bhi(xv0.z) + bhi(cv0.z), 0.f) + fmaxf(bhi(xv1.z) + bhi(cv1.z), 0.f)
                + fmaxf(bhi(xv2.z) + bhi(cv2.z), 0.f) + fmaxf(bhi(xv3.z) + bhi(cv3.z), 0.f);
        acc[6] += fmaxf(blo(xv0.w) + blo(cv0.w), 0.f) + fmaxf(blo(xv1.w) + blo(cv1.w), 0.f)
                + fmaxf(blo(xv2.w) + blo(cv2.w), 0.f) + fmaxf(blo(xv3.w) + blo(cv3.w), 0.f);
        acc[7] += fmaxf(bhi(xv0.w) + bhi(cv0.w), 0.f) + fmaxf(bhi(xv1.w) + bhi(cv1.w), 0.f)
                + fmaxf(bhi(xv2.w) + bhi(cv2.w), 0.f) + fmaxf(bhi(xv3.w) + bhi(cv3.w), 0.f);
    }
    // reduce across the 4 edge sub-groups (lanes differing in bits 4,5)
#pragma unroll
    for (int i = 0; i < 8; ++i) {
        acc[i] += __shfl_xor(acc[i], 16, 64);
        acc[i] += __shfl_xor(acc[i], 32, 64);
    }
    if (lane < 16) {
        uint4 self = *(const uint4*)&xin[(size_t)node * DD + f];
        uint4 o;
        o.x = pk2(acc[0] + blo(self.x), acc[1] + bhi(self.x));
        o.y = pk2(acc[2] + blo(self.y), acc[3] + bhi(self.y));
        o.z = pk2(acc[4] + blo(self.z), acc[5] + bhi(self.z));
        o.w = pk2(acc[6] + blo(self.w), acc[7] + bhi(self.w));
        *(uint4*)&hin[(size_t)node * DD + f] = o;
    }
}

// ========== fused conv + pooling epilogue: relu(bn2(relu(bn1(h@W1+b1))@W2+b2)) ==========
__launch_bounds__(256)
__global__ void conv_fused(const unsigned short* __restrict__ hin,
                           const short* __restrict__ Wt1, const short* __restrict__ Wt2,
                           const float* __restrict__ b1, const float* __restrict__ g1,
                           const float* __restrict__ be1, const float* __restrict__ m1,
                           const float* __restrict__ v1,
                           const float* __restrict__ b2, const float* __restrict__ g2,
                           const float* __restrict__ be2, const float* __restrict__ m2,
                           const float* __restrict__ v2,
                           const int* __restrict__ batch,
                           unsigned short* __restrict__ outb,
                           float* __restrict__ pool_slot) {
    __shared__ short As[64 * 136];
    __shared__ int sbg[64];
    const int tid  = threadIdx.x;
    const int lane = tid & 63;
    const int wave = tid >> 6;
    const int row0 = blockIdx.x * 64;

    const int col   = wave * 32 + (lane & 31);
    const int khalf = (lane >> 5) * 8;
    const int arow  = lane & 31;
    const int rbase = 4 * (lane >> 5);
    const int gmin  = batch[row0];

    short8 bf[8];
#pragma unroll
    for (int ch = 0; ch < 8; ++ch)
        bf[ch] = *(const short8*)&Wt1[col * DD + ch * 16 + khalf];

    const float sc1 = g1[col] * rsqrtf(v1[col] + BN_EPS);
    const float sh1 = fmaf(b1[col] - m1[col], sc1, be1[col]);
    const float sc2 = g2[col] * rsqrtf(v2[col] + BN_EPS);
    const float sh2 = fmaf(b2[col] - m2[col], sc2, be2[col]);

    if (tid < 64) {
        int row = row0 + tid;
        sbg[tid] = (row < NN) ? batch[row] - gmin : -1;
    }
    for (int i = tid; i < 1024; i += 256) {
        int r = i >> 4, c8 = (i & 15) * 8;
        int row = row0 + r;
        uint4 z = make_uint4(0, 0, 0, 0);
        if (row < NN) z = *(const uint4*)&hin[(size_t)row * DD + c8];
        *(uint4*)&As[r * 136 + c8] = z;
    }
    __syncthreads();

    float16 acc0 = {0.f,0.f,0.f,0.f,0.f,0.f,0.f,0.f,0.f,0.f,0.f,0.f,0.f,0.f,0.f,0.f};
    float16 acc1 = acc0;
#pragma unroll
    for (int ch = 0; ch < 8; ++ch) {
        short8 a0 = *(const short8*)&As[(arow     ) * 136 + ch * 16 + khalf];
        short8 a1 = *(const short8*)&As[(32 + arow) * 136 + ch * 16 + khalf];
        acc0 = __builtin_amdgcn_mfma_f32_32x32x16_bf16(a0, bf[ch], acc0, 0, 0, 0);
        acc1 = __builtin_amdgcn_mfma_f32_32x32x16_bf16(a1, bf[ch], acc1, 0, 0, 0);
    }

#pragma unroll
    for (int ch = 0; ch < 8; ++ch)
        bf[ch] = *(const short8*)&Wt2[col * DD + ch * 16 + khalf];

    __syncthreads();
#pragma unroll
    for (int r = 0; r < 16; ++r) {
        int rl = (r & 3) + 8 * (r >> 2) + rbase;
        As[rl * 136 + col]        = (short)f2b(fmaxf(fmaf(acc0[r], sc1, sh1), 0.f));
        As[(32 + rl) * 136 + col] = (short)f2b(fmaxf(fmaf(acc1[r], sc1, sh1), 0.f));
    }
    __syncthreads();

    acc0 = acc1 = float16{0.f,0.f,0.f,0.f,0.f,0.f,0.f,0.f,0.f,0.f,0.f,0.f,0.f,0.f,0.f,0.f};
#pragma unroll
    for (int ch = 0; ch < 8; ++ch) {
        short8 a0 = *(const short8*)&As[(arow     ) * 136 + ch * 16 + khalf];
        short8 a1 = *(const short8*)&As[(32 + arow) * 136 + ch * 16 + khalf];
        acc0 = __builtin_amdgcn_mfma_f32_32x32x16_bf16(a0, bf[ch], acc0, 0, 0, 0);
        acc1 = __builtin_amdgcn_mfma_f32_32x32x16_bf16(a1, bf[ch], acc1, 0, 0, 0);
    }

    float pg0 = 0.f, pg1 = 0.f, pg2 = 0.f, pg3 = 0.f;
#pragma unroll
    for (int r = 0; r < 16; ++r) {
        int rl  = (r & 3) + 8 * (r >> 2) + rbase;
        int row = row0 + rl;
        float v0 = fmaxf(fmaf(acc0[r], sc2, sh2), 0.f);
        float v1_ = fmaxf(fmaf(acc1[r], sc2, sh2), 0.f);
        if (row < NN)      outb[(size_t)row * DD + col]        = f2b(v0);
        if (row + 32 < NN) outb[(size_t)(row + 32) * DD + col] = f2b(v1_);
        int ga = sbg[rl], gb = sbg[rl + 32];
        pg0 += ((ga == 0) ? v0 : 0.f) + ((gb == 0) ? v1_ : 0.f);
        pg1 += ((ga == 1) ? v0 : 0.f) + ((gb == 1) ? v1_ : 0.f);
        pg2 += ((ga == 2) ? v0 : 0.f) + ((gb == 2) ? v1_ : 0.f);
        pg3 += ((ga == 3) ? v0 : 0.f) + ((gb == 3) ? v1_ : 0.f);
    }
    pg0 += __shfl_down(pg0, 32);
    pg1 += __shfl_down(pg1, 32);
    pg2 += __shfl_down(pg2, 32);
    pg3 += __shfl_down(pg3, 32);
    if (lane < 32) {
        if (pg0 != 0.f)                  atomicAdd(&pool_slot[(gmin    ) * DD + col], pg0);
        if (pg1 != 0.f && gmin + 1 < GG) atomicAdd(&pool_slot[(gmin + 1) * DD + col], pg1);
        if (pg2 != 0.f && gmin + 2 < GG) atomicAdd(&pool_slot[(gmin + 2) * DD + col], pg2);
        if (pg3 != 0.f && gmin + 3 < GG) atomicAdd(&pool_slot[(gmin + 3) * DD + col], pg3);
    }
}

// ====== final head: out[g,:] = inv[g]*sum_l pooled_l@fcw_l + sum_l fcb_l ======
__launch_bounds__(64)
__global__ void head(const float* __restrict__ pooled, const float* __restrict__ inv,
                     const float* __restrict__ fcw, const float* __restrict__ fcb,
                     float* __restrict__ out) {
    int g = blockIdx.x, t = threadIdx.x;
    __shared__ float part[LL + 1][OO];
    if (t < (LL + 1) * OO) {
        int l = t / OO, o2 = t - l * OO;
        const float* p = pooled + ((size_t)l * GG + g) * DD;
        const float* w = fcw + (size_t)l * DD * OO + o2;
        float s = 0.f;
        for (int d2 = 0; d2 < DD; ++d2) s = fmaf(p[d2], w[(size_t)d2 * OO], s);
        part[l][o2] = s;
    }
    __syncthreads();
    if (t < OO) {
        float sp = 0.f, sb2 = 0.f;
#pragma unroll
        for (int l = 0; l < LL + 1; ++l) { sp += part[l][t]; sb2 += fcb[l * OO + t]; }
        out[g * OO + t] = sp * inv[g] + sb2;
    }
}

extern "C" void kernel_launch(void* const* d_in, const int* in_sizes, int n_in,
                              void* d_out, int out_size, void* d_ws, size_t ws_size,
                              hipStream_t stream) {
    const float* x_in    = (const float*)d_in[0];
    const int*   ei      = (const int*)d_in[1];
    const int*   eattr   = (const int*)d_in[2];
    const int*   batch   = (const int*)d_in[3];
    const float* bond    = (const float*)d_in[4];
    const float* conv_w1 = (const float*)d_in[5];
    const float* conv_b1 = (const float*)d_in[6];
    const float* cbg     = (const float*)d_in[7];
    const float* cbb     = (const float*)d_in[8];
    const float* cbm     = (const float*)d_in[9];
    const float* cbv     = (const float*)d_in[10];
    const float* conv_w2 = (const float*)d_in[11];
    const float* conv_b2 = (const float*)d_in[12];
    const float* bg      = (const float*)d_in[13];
    const float* bb      = (const float*)d_in[14];
    const float* bm      = (const float*)d_in[15];
    const float* bv      = (const float*)d_in[16];
    const float* fcw     = (const float*)d_in[17];
    const float* fcb     = (const float*)d_in[18];
    float* out = (float*)d_out;

    // ---- workspace carve-up (16B-aligned chunks) ----
    char* base = (char*)d_ws;
    size_t o = 0;
    auto carve = [&](size_t bytes) { void* p = base + o; o += (bytes + 15) & ~(size_t)15; return p; };
    unsigned short* xbA    = (unsigned short*)carve((size_t)NN * DD * 2);
    unsigned short* xbB    = (unsigned short*)carve((size_t)NN * DD * 2);
    unsigned short* combo  = (unsigned short*)carve((size_t)LL * CPAD * DD * 2);
    short*          wt     = (short*)carve((size_t)10 * DD * DD * 2);
    float*          inv    = (float*)carve(GG * 4);
    // contiguous zero-region: epos | pooled[6][G][D]
    const size_t ZBYTES = (size_t)NN * 4 + (size_t)(LL + 1) * GG * DD * 4;
    int*            epos   = (int*)carve(ZBYTES);
    float*          pooled = (float*)((char*)epos + (size_t)NN * 4);
    unsigned*       e_info = (unsigned*)carve((size_t)NN * ESTRIDE * 4);

    hipMemsetAsync(epos, 0, ZBYTES, stream);

    prep<<<B_PREP, 256, 0, stream>>>(x_in, batch, bond, conv_w1, conv_w2,
                                     (unsigned*)xbA, combo, wt, e_info, inv, pooled);
    scatter_edges<<<(EE + 255) / 256, 256, 0, stream>>>(ei, eattr, epos, e_info);

    const int conv_blocks = (NN + 63) / 64;     // 782
    const int aggr_blocks = (NN + 3) / 4;       // 12500
    unsigned short* xin  = xbA;   // activation buffer (stable across layers)
    unsigned short* xout = xbB;   // hin scratch
    for (int i = 0; i < LL; ++i) {
        aggr_csr<<<aggr_blocks, 256, 0, stream>>>(
            xin, epos, e_info, combo + (size_t)i * CPAD * DD, xout);
        conv_fused<<<conv_blocks, 256, 0, stream>>>(
            xout, wt + (size_t)i * DD * DD, wt + (size_t)(5 + i) * DD * DD,
            conv_b1 + (size_t)i * DD, cbg + (size_t)i * DD, cbb + (size_t)i * DD,
            cbm + (size_t)i * DD, cbv + (size_t)i * DD,
            conv_b2 + (size_t)i * DD, bg + (size_t)i * DD, bb + (size_t)i * DD,
            bm + (size_t)i * DD, bv + (size_t)i * DD,
            batch, xin, pooled + (size_t)(i + 1) * GG * DD);
    }
    head<<<GG, 64, 0, stream>>>(pooled, inv, fcw, fcb, out);
}

// Round 10
// 420.924 us; speedup vs baseline: 1.0573x; 1.0573x over previous
//
#include <hip/hip_runtime.h>

#define NN 50000
#define EE 600000
#define DD 128
#define GG 256
#define LL 5
#define OO 10
#define BN_EPS 1e-5f
#define CPAD 513      // 512 combos + 1 sentinel (-1e30) row per layer
#define ESTRIDE 40    // fixed CSR slots per node (P(deg>40)~1e-9 at lambda=12)
#define SENT (512u << 16)

// prep kernel block-range sizes (scatter FIRST: latency-bound, overlaps the rest)
#define B_SCAT  2344                       // ceil(EE/256)
#define B_CVT   3125                       // NN*DD/8 / 256
#define B_COMBO 1283                       // ceil(LL*CPAD*DD / 256)
#define B_WT    160                        // 10 mats x 16 (32x32) tiles
#define B_INV   1
#define B_POOL0 391                        // ceil(NN/128)
#define B_PREP  (B_SCAT + B_CVT + B_COMBO + B_WT + B_INV + B_POOL0)

typedef __attribute__((ext_vector_type(8))) short short8;
typedef __attribute__((ext_vector_type(16))) float float16;

__device__ __forceinline__ unsigned short f2b(float f) {   // fp32 -> bf16 RNE
    unsigned u = __float_as_uint(f);
    unsigned r = u + 0x7FFFu + ((u >> 16) & 1u);
    return (unsigned short)(r >> 16);
}
__device__ __forceinline__ unsigned pk2(float lo, float hi) {
    return (unsigned)f2b(lo) | ((unsigned)f2b(hi) << 16);
}
__device__ __forceinline__ float blo(unsigned u) { return __uint_as_float(u << 16); }
__device__ __forceinline__ float bhi(unsigned u) { return __uint_as_float(u & 0xFFFF0000u); }

// == mega prep: edge-scatter | cvt_x | combo | Wt-transpose | inv | pool0 (all independent) ==
__launch_bounds__(256)
__global__ void prep(const float* __restrict__ x, const int* __restrict__ ei,
                     const int* __restrict__ eattr, const int* __restrict__ batch,
                     const float* __restrict__ bond,
                     const float* __restrict__ w1, const float* __restrict__ w2,
                     unsigned* __restrict__ xb4, unsigned short* __restrict__ combo,
                     short* __restrict__ wt, int* __restrict__ epos,
                     unsigned* __restrict__ e_info,
                     float* __restrict__ inv, float* __restrict__ pooled0) {
    const int bid = blockIdx.x, t = threadIdx.x;
    if (bid < B_SCAT) {
        // scatter edges into fixed-stride CSR. Only dep: epos==0 (memset before launch).
        int e = bid * 256 + t;
        if (e < EE) {
            int dst = ei[EE + e];
            int slot = atomicAdd(&epos[dst], 1);
            if (slot < ESTRIDE) {
                unsigned cidx = (unsigned)eattr[e * 3 + 0] | ((unsigned)eattr[e * 3 + 1] << 3)
                              | ((unsigned)eattr[e * 3 + 2] << 6);
                e_info[dst * ESTRIDE + slot] = (unsigned)ei[e] | (cidx << 16);
            }
        }
    } else if (bid < B_SCAT + B_CVT) {
        // x (fp32) -> xb (bf16), 8 elems/thread
        int gid = (bid - B_SCAT) * 256 + t;
        const float4* xp = (const float4*)(x + (size_t)gid * 8);
        float4 a = xp[0], b = xp[1];
        uint4 o;
        o.x = pk2(a.x, a.y); o.y = pk2(a.z, a.w);
        o.z = pk2(b.x, b.y); o.w = pk2(b.z, b.w);
        ((uint4*)xb4)[gid] = o;
    } else if (bid < B_SCAT + B_CVT + B_COMBO) {
        int e = (bid - B_SCAT - B_CVT) * 256 + t;
        if (e < LL * CPAD * DD) {
            int l = e / (CPAD * DD), rem = e - l * (CPAD * DD);
            int c = rem / DD, d = rem - c * DD;
            float s;
            if (c == 512) s = -1e30f;                     // sentinel row: relu(x+s)==0
            else {
                const float* b_ = bond + (size_t)l * 3 * 8 * DD;
                s = b_[(c & 7) * DD + d] + b_[(8 + ((c >> 3) & 7)) * DD + d]
                  + b_[(16 + (c >> 6)) * DD + d];
            }
            combo[e] = f2b(s);
        }
    } else if (bid < B_SCAT + B_CVT + B_COMBO + B_WT) {
        // coalesced transpose: wt[mat][c][k] = bf16(W[mat][k][c]), 32x32 LDS tiles
        __shared__ float tile[32][33];
        int b = bid - B_SCAT - B_CVT - B_COMBO;
        int mat = b >> 4, tl = b & 15;
        int k0 = (tl >> 2) * 32, c0 = (tl & 3) * 32;
        const float* W = (mat < 5) ? (w1 + (size_t)mat * DD * DD)
                                   : (w2 + (size_t)(mat - 5) * DD * DD);
        int j = t & 31, q = t >> 5;
#pragma unroll
        for (int rr = 0; rr < 4; ++rr) {
            int row = q + rr * 8;
            tile[row][j] = W[(size_t)(k0 + row) * DD + c0 + j];
        }
        __syncthreads();
#pragma unroll
        for (int rr = 0; rr < 4; ++rr) {
            int cr = q + rr * 8;
            wt[(size_t)mat * DD * DD + (size_t)(c0 + cr) * DD + k0 + j] = (short)f2b(tile[j][cr]);
        }
    } else if (bid < B_SCAT + B_CVT + B_COMBO + B_WT + B_INV) {
        // inv[g] via binary search on sorted batch
        __shared__ int sg[GG + 1];
        int g = t, lo = 0, hi = NN;
        while (lo < hi) { int m = (lo + hi) >> 1; if (batch[m] < g) lo = m + 1; else hi = m; }
        sg[g] = lo;
        if (g == 0) sg[GG] = NN;
        __syncthreads();
        inv[g] = 1.0f / fmaxf((float)(sg[g + 1] - sg[g]), 1.0f);
    } else {
        // layer-0 pooling of raw fp32 x: 128 nodes/block, per-graph partials
        int b = bid - (B_SCAT + B_CVT + B_COMBO + B_WT + B_INV);
        int n0 = b * 128;
        __shared__ int sb[128];
        __shared__ float part[4][DD];
        if (t < 128) { int row = n0 + t; sb[t] = (row < NN) ? batch[row] : -1; }
        ((float*)part)[t] = 0.f;
        ((float*)part)[t + 256] = 0.f;
        __syncthreads();
        int gmin = sb[0];
        int col = t & 127, rh = t >> 7;
        float pg[4] = {0.f, 0.f, 0.f, 0.f};
        for (int r = rh; r < 128; r += 2) {
            int s = sb[r];
            float v = (s >= 0) ? x[(size_t)(n0 + r) * DD + col] : 0.f;
            int dg = s - gmin;
#pragma unroll
            for (int jj = 0; jj < 4; ++jj) pg[jj] += (dg == jj) ? v : 0.f;
        }
#pragma unroll
        for (int jj = 0; jj < 4; ++jj)
            if (pg[jj] != 0.f) atomicAdd(&part[jj][col], pg[jj]);
        __syncthreads();
        for (int q2 = t; q2 < 4 * DD; q2 += 256) {
            int jj = q2 >> 7, c2 = q2 & 127;
            float v = part[jj][c2];
            if (v != 0.f && gmin + jj < GG) atomicAdd(&pooled0[(gmin + jj) * DD + c2], v);
        }
    }
}

// ====== CSR aggregation + residual: 16 lanes x 8 feats per edge, 8 edges/iter, masked tail ======
// hin = x + sum relu(x_src + combo); bf16 in/out, fp32 accumulate. No physical sentinels:
// out-of-degree slots are replaced in-register by SENT (combo row 512 = -1e30 -> relu 0).
__launch_bounds__(256)
__global__ void aggr_csr(const unsigned short* __restrict__ xin,
                         const int* __restrict__ epos,
                         const unsigned* __restrict__ e_info,
                         const unsigned short* __restrict__ combo,
                         unsigned short* __restrict__ hin) {
    int node = blockIdx.x * 4 + (threadIdx.x >> 6);
    int lane = threadIdx.x & 63;
    if (node >= NN) return;
    const int base = node * ESTRIDE;
    int deg = epos[node]; if (deg > ESTRIDE) deg = ESTRIDE;
    const int dend = base + deg;
    const int pe   = base + ((deg + 7) & ~7);
    const int eg   = lane >> 4;          // edge sub-group 0..3
    const int f    = (lane & 15) * 8;    // feature offset
    float acc[8];
#pragma unroll
    for (int i = 0; i < 8; ++i) acc[i] = 0.f;

    for (int p = base; p < pe; p += 8) {
        unsigned i0 = e_info[p + eg];         // in-bounds always; garbage masked below
        unsigned i1 = e_info[p + 4 + eg];
        if (p + eg >= dend)     i0 = SENT;
        if (p + 4 + eg >= dend) i1 = SENT;
        uint4 xv0 = *(const uint4*)&xin[(size_t)(i0 & 0xFFFFu) * DD + f];
        uint4 cv0 = *(const uint4*)&combo[(size_t)(i0 >> 16) * DD + f];
        uint4 xv1 = *(const uint4*)&xin[(size_t)(i1 & 0xFFFFu) * DD + f];
        uint4 cv1 = *(const uint4*)&combo[(size_t)(i1 >> 16) * DD + f];
        acc[0] += fmaxf(blo(xv0.x) + blo(cv0.x), 0.f) + fmaxf(blo(xv1.x) + blo(cv1.x), 0.f);
        acc[1] += fmaxf(bhi(xv0.x) + bhi(cv0.x), 0.f) + fmaxf(bhi(xv1.x) + bhi(cv1.x), 0.f);
        acc[2] += fmaxf(blo(xv0.y) + blo(cv0.y), 0.f) + fmaxf(blo(xv1.y) + blo(cv1.y), 0.f);
        acc[3] += fmaxf(bhi(xv0.y) + bhi(cv0.y), 0.f) + fmaxf(bhi(xv1.y) + bhi(cv1.y), 0.f);
        acc[4] += fmaxf(blo(xv0.z) + blo(cv0.z), 0.f) + fmaxf(blo(xv1.z) + blo(cv1.z), 0.f);
        acc[5] += fmaxf(bhi(xv0.z) + bhi(cv0.z), 0.f) + fmaxf(bhi(xv1.z) + bhi(cv1.z), 0.f);
        acc[6] += fmaxf(blo(xv0.w) + blo(cv0.w), 0.f) + fmaxf(blo(xv1.w) + blo(cv1.w), 0.f);
        acc[7] += fmaxf(bhi(xv0.w) + bhi(cv0.w), 0.f) + fmaxf(bhi(xv1.w) + bhi(cv1.w), 0.f);
    }
    // reduce across the 4 edge sub-groups (lanes differing in bits 4,5)
#pragma unroll
    for (int i = 0; i < 8; ++i) {
        acc[i] += __shfl_xor(acc[i], 16, 64);
        acc[i] += __shfl_xor(acc[i], 32, 64);
    }
    if (lane < 16) {
        uint4 self = *(const uint4*)&xin[(size_t)node * DD + f];
        uint4 o;
        o.x = pk2(acc[0] + blo(self.x), acc[1] + bhi(self.x));
        o.y = pk2(acc[2] + blo(self.y), acc[3] + bhi(self.y));
        o.z = pk2(acc[4] + blo(self.z), acc[5] + bhi(self.z));
        o.w = pk2(acc[6] + blo(self.w), acc[7] + bhi(self.w));
        *(uint4*)&hin[(size_t)node * DD + f] = o;
    }
}

// ========== fused conv + pooling epilogue: relu(bn2(relu(bn1(h@W1+b1))@W2+b2)) ==========
__launch_bounds__(256)
__global__ void conv_fused(const unsigned short* __restrict__ hin,
                           const short* __restrict__ Wt1, const short* __restrict__ Wt2,
                           const float* __restrict__ b1, const float* __restrict__ g1,
                           const float* __restrict__ be1, const float* __restrict__ m1,
                           const float* __restrict__ v1,
                           const float* __restrict__ b2, const float* __restrict__ g2,
                           const float* __restrict__ be2, const float* __restrict__ m2,
                           const float* __restrict__ v2,
                           const int* __restrict__ batch,
                           unsigned short* __restrict__ outb,
                           float* __restrict__ pool_slot) {
    __shared__ short As[64 * 136];
    __shared__ int sbg[64];
    const int tid  = threadIdx.x;
    const int lane = tid & 63;
    const int wave = tid >> 6;
    const int row0 = blockIdx.x * 64;

    const int col   = wave * 32 + (lane & 31);
    const int khalf = (lane >> 5) * 8;
    const int arow  = lane & 31;
    const int rbase = 4 * (lane >> 5);
    const int gmin  = batch[row0];

    short8 bf[8];
#pragma unroll
    for (int ch = 0; ch < 8; ++ch)
        bf[ch] = *(const short8*)&Wt1[col * DD + ch * 16 + khalf];

    const float sc1 = g1[col] * rsqrtf(v1[col] + BN_EPS);
    const float sh1 = fmaf(b1[col] - m1[col], sc1, be1[col]);
    const float sc2 = g2[col] * rsqrtf(v2[col] + BN_EPS);
    const float sh2 = fmaf(b2[col] - m2[col], sc2, be2[col]);

    if (tid < 64) {
        int row = row0 + tid;
        sbg[tid] = (row < NN) ? batch[row] - gmin : -1;
    }
    for (int i = tid; i < 1024; i += 256) {
        int r = i >> 4, c8 = (i & 15) * 8;
        int row = row0 + r;
        uint4 z = make_uint4(0, 0, 0, 0);
        if (row < NN) z = *(const uint4*)&hin[(size_t)row * DD + c8];
        *(uint4*)&As[r * 136 + c8] = z;
    }
    __syncthreads();

    float16 acc0 = {0.f,0.f,0.f,0.f,0.f,0.f,0.f,0.f,0.f,0.f,0.f,0.f,0.f,0.f,0.f,0.f};
    float16 acc1 = acc0;
#pragma unroll
    for (int ch = 0; ch < 8; ++ch) {
        short8 a0 = *(const short8*)&As[(arow     ) * 136 + ch * 16 + khalf];
        short8 a1 = *(const short8*)&As[(32 + arow) * 136 + ch * 16 + khalf];
        acc0 = __builtin_amdgcn_mfma_f32_32x32x16_bf16(a0, bf[ch], acc0, 0, 0, 0);
        acc1 = __builtin_amdgcn_mfma_f32_32x32x16_bf16(a1, bf[ch], acc1, 0, 0, 0);
    }

#pragma unroll
    for (int ch = 0; ch < 8; ++ch)
        bf[ch] = *(const short8*)&Wt2[col * DD + ch * 16 + khalf];

    __syncthreads();
#pragma unroll
    for (int r = 0; r < 16; ++r) {
        int rl = (r & 3) + 8 * (r >> 2) + rbase;
        As[rl * 136 + col]        = (short)f2b(fmaxf(fmaf(acc0[r], sc1, sh1), 0.f));
        As[(32 + rl) * 136 + col] = (short)f2b(fmaxf(fmaf(acc1[r], sc1, sh1), 0.f));
    }
    __syncthreads();

    acc0 = acc1 = float16{0.f,0.f,0.f,0.f,0.f,0.f,0.f,0.f,0.f,0.f,0.f,0.f,0.f,0.f,0.f,0.f};
#pragma unroll
    for (int ch = 0; ch < 8; ++ch) {
        short8 a0 = *(const short8*)&As[(arow     ) * 136 + ch * 16 + khalf];
        short8 a1 = *(const short8*)&As[(32 + arow) * 136 + ch * 16 + khalf];
        acc0 = __builtin_amdgcn_mfma_f32_32x32x16_bf16(a0, bf[ch], acc0, 0, 0, 0);
        acc1 = __builtin_amdgcn_mfma_f32_32x32x16_bf16(a1, bf[ch], acc1, 0, 0, 0);
    }

    float pg0 = 0.f, pg1 = 0.f, pg2 = 0.f, pg3 = 0.f;
#pragma unroll
    for (int r = 0; r < 16; ++r) {
        int rl  = (r & 3) + 8 * (r >> 2) + rbase;
        int row = row0 + rl;
        float v0 = fmaxf(fmaf(acc0[r], sc2, sh2), 0.f);
        float v1_ = fmaxf(fmaf(acc1[r], sc2, sh2), 0.f);
        if (row < NN)      outb[(size_t)row * DD + col]        = f2b(v0);
        if (row + 32 < NN) outb[(size_t)(row + 32) * DD + col] = f2b(v1_);
        int ga = sbg[rl], gb = sbg[rl + 32];
        pg0 += ((ga == 0) ? v0 : 0.f) + ((gb == 0) ? v1_ : 0.f);
        pg1 += ((ga == 1) ? v0 : 0.f) + ((gb == 1) ? v1_ : 0.f);
        pg2 += ((ga == 2) ? v0 : 0.f) + ((gb == 2) ? v1_ : 0.f);
        pg3 += ((ga == 3) ? v0 : 0.f) + ((gb == 3) ? v1_ : 0.f);
    }
    pg0 += __shfl_down(pg0, 32);
    pg1 += __shfl_down(pg1, 32);
    pg2 += __shfl_down(pg2, 32);
    pg3 += __shfl_down(pg3, 32);
    if (lane < 32) {
        if (pg0 != 0.f)                  atomicAdd(&pool_slot[(gmin    ) * DD + col], pg0);
        if (pg1 != 0.f && gmin + 1 < GG) atomicAdd(&pool_slot[(gmin + 1) * DD + col], pg1);
        if (pg2 != 0.f && gmin + 2 < GG) atomicAdd(&pool_slot[(gmin + 2) * DD + col], pg2);
        if (pg3 != 0.f && gmin + 3 < GG) atomicAdd(&pool_slot[(gmin + 3) * DD + col], pg3);
    }
}

// ====== final head: out[g,:] = inv[g]*sum_l pooled_l@fcw_l + sum_l fcb_l ======
__launch_bounds__(64)
__global__ void head(const float* __restrict__ pooled, const float* __restrict__ inv,
                     const float* __restrict__ fcw, const float* __restrict__ fcb,
                     float* __restrict__ out) {
    int g = blockIdx.x, t = threadIdx.x;
    __shared__ float part[LL + 1][OO];
    if (t < (LL + 1) * OO) {
        int l = t / OO, o2 = t - l * OO;
        const float* p = pooled + ((size_t)l * GG + g) * DD;
        const float* w = fcw + (size_t)l * DD * OO + o2;
        float s = 0.f;
        for (int d2 = 0; d2 < DD; ++d2) s = fmaf(p[d2], w[(size_t)d2 * OO], s);
        part[l][o2] = s;
    }
    __syncthreads();
    if (t < OO) {
        float sp = 0.f, sb2 = 0.f;
#pragma unroll
        for (int l = 0; l < LL + 1; ++l) { sp += part[l][t]; sb2 += fcb[l * OO + t]; }
        out[g * OO + t] = sp * inv[g] + sb2;
    }
}

extern "C" void kernel_launch(void* const* d_in, const int* in_sizes, int n_in,
                              void* d_out, int out_size, void* d_ws, size_t ws_size,
                              hipStream_t stream) {
    const float* x_in    = (const float*)d_in[0];
    const int*   ei      = (const int*)d_in[1];
    const int*   eattr   = (const int*)d_in[2];
    const int*   batch   = (const int*)d_in[3];
    const float* bond    = (const float*)d_in[4];
    const float* conv_w1 = (const float*)d_in[5];
    const float* conv_b1 = (const float*)d_in[6];
    const float* cbg     = (const float*)d_in[7];
    const float* cbb     = (const float*)d_in[8];
    const float* cbm     = (const float*)d_in[9];
    const float* cbv     = (const float*)d_in[10];
    const float* conv_w2 = (const float*)d_in[11];
    const float* conv_b2 = (const float*)d_in[12];
    const float* bg      = (const float*)d_in[13];
    const float* bb      = (const float*)d_in[14];
    const float* bm      = (const float*)d_in[15];
    const float* bv      = (const float*)d_in[16];
    const float* fcw     = (const float*)d_in[17];
    const float* fcb     = (const float*)d_in[18];
    float* out = (float*)d_out;

    // ---- workspace carve-up (16B-aligned chunks) ----
    char* base = (char*)d_ws;
    size_t o = 0;
    auto carve = [&](size_t bytes) { void* p = base + o; o += (bytes + 15) & ~(size_t)15; return p; };
    unsigned short* xbA    = (unsigned short*)carve((size_t)NN * DD * 2);
    unsigned short* xbB    = (unsigned short*)carve((size_t)NN * DD * 2);
    unsigned short* combo  = (unsigned short*)carve((size_t)LL * CPAD * DD * 2);
    short*          wt     = (short*)carve((size_t)10 * DD * DD * 2);
    float*          inv    = (float*)carve(GG * 4);
    // contiguous zero-region: epos | pooled[6][G][D]
    const size_t ZBYTES = (size_t)NN * 4 + (size_t)(LL + 1) * GG * DD * 4;
    int*            epos   = (int*)carve(ZBYTES);
    float*          pooled = (float*)((char*)epos + (size_t)NN * 4);
    unsigned*       e_info = (unsigned*)carve((size_t)NN * ESTRIDE * 4);

    hipMemsetAsync(epos, 0, ZBYTES, stream);

    prep<<<B_PREP, 256, 0, stream>>>(x_in, ei, eattr, batch, bond, conv_w1, conv_w2,
                                     (unsigned*)xbA, combo, wt, epos, e_info, inv, pooled);

    const int conv_blocks = (NN + 63) / 64;     // 782
    const int aggr_blocks = (NN + 3) / 4;       // 12500
    unsigned short* xin  = xbA;   // activation buffer (stable across layers)
    unsigned short* xout = xbB;   // hin scratch
    for (int i = 0; i < LL; ++i) {
        aggr_csr<<<aggr_blocks, 256, 0, stream>>>(
            xin, epos, e_info, combo + (size_t)i * CPAD * DD, xout);
        conv_fused<<<conv_blocks, 256, 0, stream>>>(
            xout, wt + (size_t)i * DD * DD, wt + (size_t)(5 + i) * DD * DD,
            conv_b1 + (size_t)i * DD, cbg + (size_t)i * DD, cbb + (size_t)i * DD,
            cbm + (size_t)i * DD, cbv + (size_t)i * DD,
            conv_b2 + (size_t)i * DD, bg + (size_t)i * DD, bb + (size_t)i * DD,
            bm + (size_t)i * DD, bv + (size_t)i * DD,
            batch, xin, pooled + (size_t)(i + 1) * GG * DD);
    }
    head<<<GG, 64, 0, stream>>>(pooled, inv, fcw, fcb, out);
}